// Round 5
// baseline (931.771 us; speedup 1.0000x reference)
//
#include <hip/hip_runtime.h>
#include <cstddef>

#define SLOPE_F (11.0f / 48.0f)

static const int NN = 50000;     // nodes
static const int EE = 1600000;   // edges per timestep
static const int D  = 256;

typedef __attribute__((ext_vector_type(8))) short short8;
typedef __attribute__((ext_vector_type(4))) float f32x4;

__device__ __forceinline__ ushort f2bf(float f) {
    unsigned u = __float_as_uint(f);
    unsigned r = (u + 0x7fffu + ((u >> 16) & 1u)) >> 16;
    return (ushort)r;
}
__device__ __forceinline__ float bf2f(ushort u) {
    return __uint_as_float(((unsigned)u) << 16);
}

// ---------------- prep mega-kernel ----------------
// blocks [0,2048): transpose-merge GRU weights -> TW[mat][k][i], mat = layer*4 + {Mz,Mr,Wh,Uh}
// blocks [2048,2304): BtW1[n][k] = bf16(W1[k][n])
// blocks [2304,2500): zero deg
__global__ __launch_bounds__(256) void prep_kernel(
        const float* __restrict__ Wz0, const float* __restrict__ Uz0,
        const float* __restrict__ Wr0, const float* __restrict__ Ur0,
        const float* __restrict__ Wh0, const float* __restrict__ Uh0,
        const float* __restrict__ Wz1, const float* __restrict__ Uz1,
        const float* __restrict__ Wr1, const float* __restrict__ Ur1,
        const float* __restrict__ Wh1, const float* __restrict__ Uh1,
        const float* __restrict__ W1,
        float* __restrict__ TW, ushort* __restrict__ BtW1, int* __restrict__ deg) {
    int b = blockIdx.x;
    int t = threadIdx.x;
    if (b < 2048) {
        int mat = b >> 8;
        int k = b & 255;
        const float* P = nullptr; const float* S = nullptr;
        switch (mat) {
            case 0: P = Wz0; S = Uz0; break;
            case 1: P = Wr0; S = Ur0; break;
            case 2: P = Wh0; break;
            case 3: P = Uh0; break;
            case 4: P = Wz1; S = Uz1; break;
            case 5: P = Wr1; S = Ur1; break;
            case 6: P = Wh1; break;
            default: P = Uh1; break;
        }
        float v = P[t * 256 + k];
        if (S) v += S[t * 256 + k];
        TW[((size_t)mat * 256 + k) * 256 + t] = v;
    } else if (b < 2304) {
        int n = b - 2048;
        BtW1[(size_t)n * 256 + t] = f2bf(W1[t * 256 + n]);
    } else {
        int i = (b - 2304) * 256 + t;
        if (i < NN) deg[i] = 0;
    }
}

// ---------------- fused GRU: 6 steps, both layers, one launch ----------------
// Column-independence: column j of Qn depends only on column j of Q.
// grid 128: layer = blk>>6, colgroup = blk&63 (4 cols each); 256 threads = rows.
__global__ __launch_bounds__(256) void gru_kernel(
        const float* __restrict__ TW,
        const float* __restrict__ bz0, const float* __restrict__ br0,
        const float* __restrict__ bh0, const float* __restrict__ Q00,
        const float* __restrict__ bz1, const float* __restrict__ br1,
        const float* __restrict__ bh1, const float* __restrict__ Q01,
        ushort* __restrict__ Bt) {
    __shared__ float qs[256][4];
    __shared__ float rqs[256][4];
    int layer = blockIdx.x >> 6;
    int j0 = (blockIdx.x & 63) * 4;
    int i = threadIdx.x;
    const float* MzT = TW + (size_t)layer * 4 * 65536;
    const float* MrT = MzT + 65536;
    const float* WhT = MzT + 2 * 65536;
    const float* UhT = MzT + 3 * 65536;
    const float* bz = layer ? bz1 : bz0;
    const float* br = layer ? br1 : br0;
    const float* bh = layer ? bh1 : bh0;
    const float* Q0 = layer ? Q01 : Q00;

    float4 bzv = *(const float4*)&bz[i * 256 + j0];
    float4 brv = *(const float4*)&br[i * 256 + j0];
    float4 bhv = *(const float4*)&bh[i * 256 + j0];
    float bza[4] = {bzv.x, bzv.y, bzv.z, bzv.w};
    float bra[4] = {brv.x, brv.y, brv.z, brv.w};
    float bha[4] = {bhv.x, bhv.y, bhv.z, bhv.w};

    float4 qv = *(const float4*)&Q0[i * 256 + j0];
    *(float4*)&qs[i][0] = qv;
    __syncthreads();

    float qn[4] = {qv.x, qv.y, qv.z, qv.w};
    for (int step = 0; step < 6; ++step) {
        float az[4] = {}, ar[4] = {}, ah[4] = {};
#pragma unroll 4
        for (int k = 0; k < 256; ++k) {
            float mz = MzT[k * 256 + i];
            float mr = MrT[k * 256 + i];
            float wh = WhT[k * 256 + i];
            float4 qk = *(const float4*)&qs[k][0];
            float qa[4] = {qk.x, qk.y, qk.z, qk.w};
#pragma unroll
            for (int c = 0; c < 4; ++c) {
                az[c] += mz * qa[c];
                ar[c] += mr * qa[c];
                ah[c] += wh * qa[c];
            }
        }
        float z[4], qo[4];
        float4 qown = *(const float4*)&qs[i][0];
        qo[0] = qown.x; qo[1] = qown.y; qo[2] = qown.z; qo[3] = qown.w;
        float4 rqv;
        float rq[4];
#pragma unroll
        for (int c = 0; c < 4; ++c) {
            z[c] = 1.f / (1.f + expf(-(az[c] + bza[c])));
            float r = 1.f / (1.f + expf(-(ar[c] + bra[c])));
            rq[c] = r * qo[c];
        }
        rqv.x = rq[0]; rqv.y = rq[1]; rqv.z = rq[2]; rqv.w = rq[3];
        *(float4*)&rqs[i][0] = rqv;
        __syncthreads();
        float bu[4] = {};
#pragma unroll 4
        for (int k = 0; k < 256; ++k) {
            float uh = UhT[k * 256 + i];
            float4 rk = *(const float4*)&rqs[k][0];
            float ra[4] = {rk.x, rk.y, rk.z, rk.w};
#pragma unroll
            for (int c = 0; c < 4; ++c) bu[c] += uh * ra[c];
        }
        float4 qnv;
#pragma unroll
        for (int c = 0; c < 4; ++c) {
            float h = tanhf(ah[c] + bu[c] + bha[c]);
            qn[c] = (1.f - z[c]) * qo[c] + z[c] * h;
        }
        qnv.x = qn[0]; qnv.y = qn[1]; qnv.z = qn[2]; qnv.w = qn[3];
        *(float4*)&qs[i][0] = qnv;
        __syncthreads();
    }
    // write in GEMM Bt layout: Bt[layer][n][k] = bf16(Qfinal[k][n]); n = j0+c, k = i
#pragma unroll
    for (int c = 0; c < 4; ++c)
        Bt[(size_t)layer * 65536 + (size_t)(j0 + c) * 256 + i] = f2bf(qn[c]);
}

// ---------------- MFMA GEMM: C(bf16)[M,256] = A[M,256] @ B[256,256] ----------------
// Bt: [n][k] bf16. Whole B staged in 128 KB LDS with XOR swizzle.
// ASRC: 0 = A bf16, 1 = A fp32 (inline convert). EPI: 0 = plain, 1 = bias+relu.
template <int ASRC, int EPI>
__global__ __launch_bounds__(512) void gemm_mfma(const ushort* __restrict__ A,
                                                 const float* __restrict__ Af,
                                                 const ushort* __restrict__ Bt,
                                                 const float* __restrict__ bias,
                                                 ushort* __restrict__ C, int M, int ntiles) {
    __shared__ ushort Bl[65536];   // 128 KB
    int tid = threadIdx.x;

#pragma unroll
    for (int i = 0; i < 16; ++i) {
        int c  = tid + i * 512;
        int L  = c << 4;
        int n  = L >> 9;
        int kb = L & 511;
        short8 v = *(const short8*)((const char*)Bt + L);
        *(short8*)((char*)Bl + n * 512 + (kb ^ ((n & 7) << 4))) = v;
    }
    __syncthreads();

    int w = tid >> 6, l = tid & 63;
    int lr = l & 15;
    int lk = l >> 4;

    for (int t = blockIdx.x; t < ntiles; t += gridDim.x) {
        int row0 = t * 128 + w * 16;
        int ra = row0 + lr; if (ra > M - 1) ra = M - 1;
        const ushort* Ap  = A  + (size_t)ra * 256 + lk * 8;
        const float*  Apf = Af + (size_t)ra * 256 + lk * 8;

        f32x4 acc[16] = {};
#pragma unroll
        for (int kc = 0; kc < 8; ++kc) {
            short8 ac;
            if (ASRC == 0) {
                ac = *(const short8*)(Ap + kc * 32);
            } else {
                float4 f0 = *(const float4*)(Apf + kc * 32);
                float4 f1 = *(const float4*)(Apf + kc * 32 + 4);
                ac[0] = (short)f2bf(f0.x); ac[1] = (short)f2bf(f0.y);
                ac[2] = (short)f2bf(f0.z); ac[3] = (short)f2bf(f0.w);
                ac[4] = (short)f2bf(f1.x); ac[5] = (short)f2bf(f1.y);
                ac[6] = (short)f2bf(f1.z); ac[7] = (short)f2bf(f1.w);
            }
            int kb = kc * 64 + lk * 16;
#pragma unroll
            for (int nb = 0; nb < 16; ++nb) {
                int n = nb * 16 + lr;
                short8 bf = *(const short8*)((const char*)Bl + n * 512 + (kb ^ ((lr & 7) << 4)));
                acc[nb] = __builtin_amdgcn_mfma_f32_16x16x32_bf16(ac, bf, acc[nb], 0, 0, 0);
            }
        }

        int ro = lk * 4;
#pragma unroll
        for (int nb = 0; nb < 16; ++nb) {
            int gc = nb * 16 + lr;
            float bb = (EPI == 1) ? bias[gc] : 0.f;
#pragma unroll
            for (int q = 0; q < 4; ++q) {
                int g = row0 + ro + q;
                if (g < M) {
                    float v = acc[nb][q];
                    if (EPI == 1) v = fmaxf(v + bb, 0.f);
                    C[(size_t)g * 256 + gc] = f2bf(v);
                }
            }
        }
    }
}

// ---------------- CSR build ----------------
__global__ void hist_kernel(const int* __restrict__ dst, int* __restrict__ deg, int nE) {
    int e = blockIdx.x * blockDim.x + threadIdx.x;
    if (e < nE) atomicAdd(&deg[dst[e]], 1);
}

// hierarchical scan: A = per-chunk exclusive scan + chunk sums
__global__ __launch_bounds__(256) void scanA_kernel(const int* __restrict__ deg,
                                                    int* __restrict__ rs,
                                                    int* __restrict__ bsum, int n) {
    __shared__ int wsum[4];
    int tid = threadIdx.x;
    int i = blockIdx.x * 256 + tid;
    int lane = tid & 63, wv = tid >> 6;
    int v = (i < n) ? deg[i] : 0;
    int x = v;
#pragma unroll
    for (int off = 1; off < 64; off <<= 1) {
        int t = __shfl_up(x, off, 64);
        if (lane >= off) x += t;
    }
    if (lane == 63) wsum[wv] = x;
    __syncthreads();
    if (tid == 0) {
        int s = 0;
#pragma unroll
        for (int q = 0; q < 4; ++q) { int t = wsum[q]; wsum[q] = s; s += t; }
        bsum[blockIdx.x] = s;
    }
    __syncthreads();
    if (i < n) rs[i] = wsum[wv] + x - v;
}

__global__ __launch_bounds__(256) void scanB_kernel(const int* __restrict__ bsum,
                                                    int* __restrict__ boff,
                                                    int* __restrict__ rs, int nb) {
    __shared__ int wsum[4];
    int tid = threadIdx.x;
    int lane = tid & 63, wv = tid >> 6;
    int v = (tid < nb) ? bsum[tid] : 0;
    int x = v;
#pragma unroll
    for (int off = 1; off < 64; off <<= 1) {
        int t = __shfl_up(x, off, 64);
        if (lane >= off) x += t;
    }
    if (lane == 63) wsum[wv] = x;
    __syncthreads();
    if (tid == 0) {
        int s = 0;
#pragma unroll
        for (int q = 0; q < 4; ++q) { int t = wsum[q]; wsum[q] = s; s += t; }
        rs[NN] = EE;
    }
    __syncthreads();
    if (tid < nb) boff[tid] = wsum[wv] + x - v;
}

__global__ __launch_bounds__(256) void scanC_kernel(int* __restrict__ rs,
                                                    int* __restrict__ cur,
                                                    const int* __restrict__ boff, int n) {
    int i = blockIdx.x * 256 + threadIdx.x;
    if (i < n) {
        int v = rs[i] + boff[blockIdx.x];
        rs[i] = v;
        cur[i] = v;
    }
}

__global__ void scatter_kernel(const int* __restrict__ src, const int* __restrict__ dst,
                               const float* __restrict__ val, int* __restrict__ cur,
                               int2* __restrict__ csr, int nE) {
    int e = blockIdx.x * blockDim.x + threadIdx.x;
    if (e < nE) {
        int p = atomicAdd(&cur[dst[e]], 1);
        csr[p] = make_int2(src[e], __float_as_int(val[e]));
    }
}

// ---------------- pull aggregation (bf16 gather) + fused RReLU -> bf16 out ----------------
__global__ __launch_bounds__(256) void agg_csr_kernel(const ushort* __restrict__ XW,
                                                      const int2* __restrict__ csr,
                                                      const int* __restrict__ rs,
                                                      ushort* __restrict__ out) {
    int d = blockIdx.x * 4 + (threadIdx.x >> 6);
    if (d >= NN) return;
    int lane = threadIdx.x & 63;
    int beg = rs[d], end = rs[d + 1];
    float ax = 0.f, ay = 0.f, az = 0.f, aw = 0.f;
    int i = beg;
    for (; i + 7 < end; i += 8) {
        int s[8]; float v[8];
#pragma unroll
        for (int u = 0; u < 8; ++u) {
            int2 sv = csr[i + u];
            s[u] = sv.x; v[u] = __int_as_float(sv.y);
        }
#pragma unroll
        for (int u = 0; u < 8; ++u) {
            ushort4 x = *(const ushort4*)&XW[(size_t)s[u] * D + lane * 4];
            ax += v[u] * bf2f(x.x);
            ay += v[u] * bf2f(x.y);
            az += v[u] * bf2f(x.z);
            aw += v[u] * bf2f(x.w);
        }
    }
    for (; i < end; ++i) {
        int2 sv = csr[i];
        float v0 = __int_as_float(sv.y);
        ushort4 x = *(const ushort4*)&XW[(size_t)sv.x * D + lane * 4];
        ax += v0 * bf2f(x.x); ay += v0 * bf2f(x.y);
        az += v0 * bf2f(x.z); aw += v0 * bf2f(x.w);
    }
    ax = (ax >= 0.f) ? ax : SLOPE_F * ax;
    ay = (ay >= 0.f) ? ay : SLOPE_F * ay;
    az = (az >= 0.f) ? az : SLOPE_F * az;
    aw = (aw >= 0.f) ? aw : SLOPE_F * aw;
    ushort4 o;
    o.x = f2bf(ax); o.y = f2bf(ay); o.z = f2bf(az); o.w = f2bf(aw);
    *(ushort4*)&out[(size_t)d * D + lane * 4] = o;
}

// ---------------- final: logits = hid@W2 + b2 ; log_softmax over 16 classes ----------------
__global__ void mlp2_kernel(const ushort* __restrict__ hid, const float* __restrict__ W2,
                            const float* __restrict__ b2, float* __restrict__ out, int M) {
    int tid = threadIdx.x;
    int n = blockIdx.x * 16 + (tid >> 4);
    int c = tid & 15;
    if (n >= M) return;
    float acc = b2[c];
    const ushort* hp = hid + (size_t)n * D;
    for (int k = 0; k < D; k += 8) {
        short8 h8 = *(const short8*)(hp + k);
#pragma unroll
        for (int u = 0; u < 8; ++u)
            acc += bf2f((ushort)h8[u]) * W2[(k + u) * 16 + c];
    }
    float m = acc;
#pragma unroll
    for (int off = 1; off < 16; off <<= 1)
        m = fmaxf(m, __shfl_xor(m, off, 16));
    float ex = expf(acc - m);
    float s = ex;
#pragma unroll
    for (int off = 1; off < 16; off <<= 1)
        s += __shfl_xor(s, off, 16);
    out[(size_t)n * 16 + c] = acc - m - logf(s);
}

extern "C" void kernel_launch(void* const* d_in, const int* in_sizes, int n_in,
                              void* d_out, int out_size, void* d_ws, size_t ws_size,
                              hipStream_t stream) {
    const float* node_feats = (const float*)d_in[0];
    const float* edge_val   = (const float*)d_in[1];
    const float* l0_Wz = (const float*)d_in[2];
    const float* l0_Uz = (const float*)d_in[3];
    const float* l0_bz = (const float*)d_in[4];
    const float* l0_Wr = (const float*)d_in[5];
    const float* l0_Ur = (const float*)d_in[6];
    const float* l0_br = (const float*)d_in[7];
    const float* l0_Wh = (const float*)d_in[8];
    const float* l0_Uh = (const float*)d_in[9];
    const float* l0_bh = (const float*)d_in[10];
    const float* l0_Q0 = (const float*)d_in[11];
    const float* l1_Wz = (const float*)d_in[12];
    const float* l1_Uz = (const float*)d_in[13];
    const float* l1_bz = (const float*)d_in[14];
    const float* l1_Wr = (const float*)d_in[15];
    const float* l1_Ur = (const float*)d_in[16];
    const float* l1_br = (const float*)d_in[17];
    const float* l1_Wh = (const float*)d_in[18];
    const float* l1_Uh = (const float*)d_in[19];
    const float* l1_bh = (const float*)d_in[20];
    const float* l1_Q0 = (const float*)d_in[21];
    const float* W1 = (const float*)d_in[22];
    const float* b1 = (const float*)d_in[23];
    const float* W2 = (const float*)d_in[24];
    const float* b2 = (const float*)d_in[25];
    const int* e_src = (const int*)d_in[26];
    const int* e_dst = (const int*)d_in[27];
    float* out = (float*)d_out;

    // workspace layout
    const size_t BIG = (size_t)NN * D;   // 12.8M elements
    ushort* XWb = (ushort*)d_ws;                 // bf16 GEMM out
    ushort* H   = XWb + BIG;                     // bf16 activations (h1/h2)
    ushort* Bt  = H + BIG;                       // 3 x 65536 bf16 (q0T, q1T, W1T)
    float*  TW  = (float*)(Bt + 3 * 65536);      // 8 x 65536 fp32 transposed GRU weights
    int2*   csr = (int2*)(TW + 8 * 65536);       // EE
    int*    deg = (int*)(csr + EE);              // NN
    int*    rs  = deg + NN;                      // NN+1
    int*    cur = rs + NN + 1;                   // NN
    int*    bsum = cur + NN;                     // 200
    int*    boff = bsum + 200;                   // 200

    // --- only timestep 5 contributes to the output ---
    const float* feats5 = node_feats + (size_t)5 * BIG;
    const int*   src5   = e_src + (size_t)5 * EE;
    const int*   dst5   = e_dst + (size_t)5 * EE;
    const float* val5   = edge_val + (size_t)5 * EE;

    // --- prep: weight transpose/merge + W1 conversion + deg zero (one launch) ---
    prep_kernel<<<2500, 256, 0, stream>>>(l0_Wz, l0_Uz, l0_Wr, l0_Ur, l0_Wh, l0_Uh,
                                          l1_Wz, l1_Uz, l1_Wr, l1_Ur, l1_Wh, l1_Uh,
                                          W1, TW, Bt + 2 * 65536, deg);

    // --- full 6-step GRU for both layers, one launch ---
    gru_kernel<<<128, 256, 0, stream>>>(TW, l0_bz, l0_br, l0_bh, l0_Q0,
                                        l1_bz, l1_br, l1_bh, l1_Q0, Bt);

    // --- CSR build (reused for both layers) ---
    const int nchunks = (NN + 255) / 256;   // 196
    hist_kernel<<<(EE + 255) / 256, 256, 0, stream>>>(dst5, deg, EE);
    scanA_kernel<<<nchunks, 256, 0, stream>>>(deg, rs, bsum, NN);
    scanB_kernel<<<1, 256, 0, stream>>>(bsum, boff, rs, nchunks);
    scanC_kernel<<<nchunks, 256, 0, stream>>>(rs, cur, boff, NN);
    scatter_kernel<<<(EE + 255) / 256, 256, 0, stream>>>(src5, dst5, val5, cur, csr, EE);

    const int ntiles = (NN + 127) / 128;        // 391
    const int gemm_blocks = (ntiles + 1) / 2;   // 196
    const int ablocks = (NN + 3) / 4;           // 12500

    // layer 0 @ t=5 (A = fp32 feats, inline convert)
    gemm_mfma<1, 0><<<gemm_blocks, 512, 0, stream>>>(nullptr, feats5, Bt + 0 * 65536,
                                                     nullptr, XWb, NN, ntiles);
    agg_csr_kernel<<<ablocks, 256, 0, stream>>>(XWb, csr, rs, H);

    // layer 1 @ t=5
    gemm_mfma<0, 0><<<gemm_blocks, 512, 0, stream>>>(H, nullptr, Bt + 1 * 65536,
                                                     nullptr, XWb, NN, ntiles);
    agg_csr_kernel<<<ablocks, 256, 0, stream>>>(XWb, csr, rs, H);

    // MLP head
    gemm_mfma<0, 1><<<gemm_blocks, 512, 0, stream>>>(H, nullptr, Bt + 2 * 65536,
                                                     b1, XWb, NN, ntiles);
    mlp2_kernel<<<(NN + 15) / 16, 256, 0, stream>>>(XWb, W2, b2, out, NN);
}

// Round 6
// 785.046 us; speedup vs baseline: 1.1869x; 1.1869x over previous
//
#include <hip/hip_runtime.h>
#include <cstddef>

#define SLOPE_F (11.0f / 48.0f)

static const int NN = 50000;     // nodes
static const int EE = 1600000;   // edges per timestep
static const int D  = 256;

typedef __attribute__((ext_vector_type(8))) short short8;
typedef __attribute__((ext_vector_type(4))) float f32x4;

__device__ __forceinline__ ushort f2bf(float f) {
    unsigned u = __float_as_uint(f);
    unsigned r = (u + 0x7fffu + ((u >> 16) & 1u)) >> 16;
    return (ushort)r;
}
__device__ __forceinline__ float bf2f(ushort u) {
    return __uint_as_float(((unsigned)u) << 16);
}

// ---------------- prep mega-kernel ----------------
// blocks [0,2048): transpose-merge GRU weights -> TW[mat][k][i]
// blocks [2048,2304): BtW1[n][k] = bf16(W1[k][n])
// blocks [2304,2500): zero deg
__global__ __launch_bounds__(256) void prep_kernel(
        const float* __restrict__ Wz0, const float* __restrict__ Uz0,
        const float* __restrict__ Wr0, const float* __restrict__ Ur0,
        const float* __restrict__ Wh0, const float* __restrict__ Uh0,
        const float* __restrict__ Wz1, const float* __restrict__ Uz1,
        const float* __restrict__ Wr1, const float* __restrict__ Ur1,
        const float* __restrict__ Wh1, const float* __restrict__ Uh1,
        const float* __restrict__ W1,
        float* __restrict__ TW, ushort* __restrict__ BtW1, int* __restrict__ deg) {
    int b = blockIdx.x;
    int t = threadIdx.x;
    if (b < 2048) {
        int mat = b >> 8;
        int k = b & 255;
        const float* P = nullptr; const float* S = nullptr;
        switch (mat) {
            case 0: P = Wz0; S = Uz0; break;
            case 1: P = Wr0; S = Ur0; break;
            case 2: P = Wh0; break;
            case 3: P = Uh0; break;
            case 4: P = Wz1; S = Uz1; break;
            case 5: P = Wr1; S = Ur1; break;
            case 6: P = Wh1; break;
            default: P = Uh1; break;
        }
        float v = P[t * 256 + k];
        if (S) v += S[t * 256 + k];
        TW[((size_t)mat * 256 + k) * 256 + t] = v;
    } else if (b < 2304) {
        int n = b - 2048;
        BtW1[(size_t)n * 256 + t] = f2bf(W1[t * 256 + n]);
    } else {
        int i = (b - 2304) * 256 + t;
        if (i < NN) deg[i] = 0;
    }
}

// ---------------- fused GRU: 6 steps, both layers, one launch ----------------
// grid 256: layer = blk>>7, colpair = blk&127 (2 cols each); 256 threads = rows.
__global__ __launch_bounds__(256) void gru_kernel(
        const float* __restrict__ TW,
        const float* __restrict__ bz0, const float* __restrict__ br0,
        const float* __restrict__ bh0, const float* __restrict__ Q00,
        const float* __restrict__ bz1, const float* __restrict__ br1,
        const float* __restrict__ bh1, const float* __restrict__ Q01,
        ushort* __restrict__ Bt) {
    __shared__ float qs[256][2];
    __shared__ float rqs[256][2];
    int layer = blockIdx.x >> 7;
    int j0 = (blockIdx.x & 127) * 2;
    int i = threadIdx.x;
    const float* MzT = TW + (size_t)layer * 4 * 65536;
    const float* MrT = MzT + 65536;
    const float* WhT = MzT + 2 * 65536;
    const float* UhT = MzT + 3 * 65536;
    const float* bz = layer ? bz1 : bz0;
    const float* br = layer ? br1 : br0;
    const float* bh = layer ? bh1 : bh0;
    const float* Q0 = layer ? Q01 : Q00;

    float2 bzv = *(const float2*)&bz[i * 256 + j0];
    float2 brv = *(const float2*)&br[i * 256 + j0];
    float2 bhv = *(const float2*)&bh[i * 256 + j0];
    float bza[2] = {bzv.x, bzv.y};
    float bra[2] = {brv.x, brv.y};
    float bha[2] = {bhv.x, bhv.y};

    float2 qv = *(const float2*)&Q0[i * 256 + j0];
    *(float2*)&qs[i][0] = qv;
    __syncthreads();

    float qn[2] = {qv.x, qv.y};
    for (int step = 0; step < 6; ++step) {
        float az[2] = {}, ar[2] = {}, ah[2] = {};
#pragma unroll 8
        for (int k = 0; k < 256; ++k) {
            float mz = MzT[k * 256 + i];
            float mr = MrT[k * 256 + i];
            float wh = WhT[k * 256 + i];
            float2 qk = *(const float2*)&qs[k][0];
            float qa[2] = {qk.x, qk.y};
#pragma unroll
            for (int c = 0; c < 2; ++c) {
                az[c] += mz * qa[c];
                ar[c] += mr * qa[c];
                ah[c] += wh * qa[c];
            }
        }
        float z[2], qo[2];
        float2 qown = *(const float2*)&qs[i][0];
        qo[0] = qown.x; qo[1] = qown.y;
        float rq[2];
#pragma unroll
        for (int c = 0; c < 2; ++c) {
            z[c] = 1.f / (1.f + expf(-(az[c] + bza[c])));
            float r = 1.f / (1.f + expf(-(ar[c] + bra[c])));
            rq[c] = r * qo[c];
        }
        float2 rqv; rqv.x = rq[0]; rqv.y = rq[1];
        *(float2*)&rqs[i][0] = rqv;
        __syncthreads();
        float bu[2] = {};
#pragma unroll 8
        for (int k = 0; k < 256; ++k) {
            float uh = UhT[k * 256 + i];
            float2 rk = *(const float2*)&rqs[k][0];
#pragma unroll
            for (int c = 0; c < 2; ++c) bu[c] += uh * ((c == 0) ? rk.x : rk.y);
        }
        float2 qnv;
#pragma unroll
        for (int c = 0; c < 2; ++c) {
            float h = tanhf(ah[c] + bu[c] + bha[c]);
            qn[c] = (1.f - z[c]) * qo[c] + z[c] * h;
        }
        qnv.x = qn[0]; qnv.y = qn[1];
        *(float2*)&qs[i][0] = qnv;
        __syncthreads();
    }
#pragma unroll
    for (int c = 0; c < 2; ++c)
        Bt[(size_t)layer * 65536 + (size_t)(j0 + c) * 256 + i] = f2bf(qn[c]);
}

// ---------------- MFMA GEMM (no LDS; B is L1/L2-resident) ----------------
// C(bf16)[M,256] = A[M,256] @ B[256,256]; Bt: [n][k] bf16.
// 256 thr = 4 waves; wave w covers rows row0+w*16 .. +15; block = 64 rows.
// ASRC: 0 = A bf16, 1 = A fp32 (inline convert). EPI: 0 = plain, 1 = bias+relu.
template <int ASRC, int EPI>
__global__ __launch_bounds__(256) void gemm_mfma(const ushort* __restrict__ A,
                                                 const float* __restrict__ Af,
                                                 const ushort* __restrict__ Bt,
                                                 const float* __restrict__ bias,
                                                 ushort* __restrict__ C, int M) {
    int tid = threadIdx.x;
    int w = tid >> 6, l = tid & 63;
    int lr = l & 15;
    int lk = l >> 4;
    int row0 = blockIdx.x * 64 + w * 16;
    int ra = row0 + lr; if (ra > M - 1) ra = M - 1;
    const ushort* Ap  = A  + (size_t)ra * 256 + lk * 8;
    const float*  Apf = Af + (size_t)ra * 256 + lk * 8;
    const ushort* Bp  = Bt + (size_t)lr * 256 + lk * 8;

    f32x4 acc[16] = {};
#pragma unroll
    for (int kc = 0; kc < 8; ++kc) {
        short8 ac;
        if (ASRC == 0) {
            ac = *(const short8*)(Ap + kc * 32);
        } else {
            float4 f0 = *(const float4*)(Apf + kc * 32);
            float4 f1 = *(const float4*)(Apf + kc * 32 + 4);
            ac[0] = (short)f2bf(f0.x); ac[1] = (short)f2bf(f0.y);
            ac[2] = (short)f2bf(f0.z); ac[3] = (short)f2bf(f0.w);
            ac[4] = (short)f2bf(f1.x); ac[5] = (short)f2bf(f1.y);
            ac[6] = (short)f2bf(f1.z); ac[7] = (short)f2bf(f1.w);
        }
#pragma unroll
        for (int nb = 0; nb < 16; ++nb) {
            short8 bf = *(const short8*)(Bp + (size_t)nb * 4096 + kc * 32);
            acc[nb] = __builtin_amdgcn_mfma_f32_16x16x32_bf16(ac, bf, acc[nb], 0, 0, 0);
        }
    }

    int ro = lk * 4;
#pragma unroll
    for (int nb = 0; nb < 16; ++nb) {
        int gc = nb * 16 + lr;
        float bb = (EPI == 1) ? bias[gc] : 0.f;
#pragma unroll
        for (int q = 0; q < 4; ++q) {
            int g = row0 + ro + q;
            if (g < M) {
                float v = acc[nb][q];
                if (EPI == 1) v = fmaxf(v + bb, 0.f);
                C[(size_t)g * 256 + gc] = f2bf(v);
            }
        }
    }
}

// ---------------- CSR build ----------------
__global__ void hist_kernel(const int* __restrict__ dst, int* __restrict__ deg, int nE) {
    int e = blockIdx.x * blockDim.x + threadIdx.x;
    if (e < nE) atomicAdd(&deg[dst[e]], 1);
}

__global__ __launch_bounds__(256) void scanA_kernel(const int* __restrict__ deg,
                                                    int* __restrict__ rs,
                                                    int* __restrict__ bsum, int n) {
    __shared__ int wsum[4];
    int tid = threadIdx.x;
    int i = blockIdx.x * 256 + tid;
    int lane = tid & 63, wv = tid >> 6;
    int v = (i < n) ? deg[i] : 0;
    int x = v;
#pragma unroll
    for (int off = 1; off < 64; off <<= 1) {
        int t = __shfl_up(x, off, 64);
        if (lane >= off) x += t;
    }
    if (lane == 63) wsum[wv] = x;
    __syncthreads();
    if (tid == 0) {
        int s = 0;
#pragma unroll
        for (int q = 0; q < 4; ++q) { int t = wsum[q]; wsum[q] = s; s += t; }
        bsum[blockIdx.x] = s;
    }
    __syncthreads();
    if (i < n) rs[i] = wsum[wv] + x - v;
}

__global__ __launch_bounds__(256) void scanB_kernel(const int* __restrict__ bsum,
                                                    int* __restrict__ boff,
                                                    int* __restrict__ rs, int nb) {
    __shared__ int wsum[4];
    int tid = threadIdx.x;
    int lane = tid & 63, wv = tid >> 6;
    int v = (tid < nb) ? bsum[tid] : 0;
    int x = v;
#pragma unroll
    for (int off = 1; off < 64; off <<= 1) {
        int t = __shfl_up(x, off, 64);
        if (lane >= off) x += t;
    }
    if (lane == 63) wsum[wv] = x;
    __syncthreads();
    if (tid == 0) {
        int s = 0;
#pragma unroll
        for (int q = 0; q < 4; ++q) { int t = wsum[q]; wsum[q] = s; s += t; }
        rs[NN] = EE;
    }
    __syncthreads();
    if (tid < nb) boff[tid] = wsum[wv] + x - v;
}

__global__ __launch_bounds__(256) void scanC_kernel(int* __restrict__ rs,
                                                    int* __restrict__ cur,
                                                    const int* __restrict__ boff, int n) {
    int i = blockIdx.x * 256 + threadIdx.x;
    if (i < n) {
        int v = rs[i] + boff[blockIdx.x];
        rs[i] = v;
        cur[i] = v;
    }
}

__global__ void scatter_kernel(const int* __restrict__ src, const int* __restrict__ dst,
                               const float* __restrict__ val, int* __restrict__ cur,
                               int2* __restrict__ csr, int nE) {
    int e = blockIdx.x * blockDim.x + threadIdx.x;
    if (e < nE) {
        int p = atomicAdd(&cur[dst[e]], 1);
        csr[p] = make_int2(src[e], __float_as_int(val[e]));
    }
}

// ---------------- pull aggregation + fused RReLU -> bf16 out ----------------
// one wave per dst; lanes 0-31 even edges, 32-63 odd edges; lane loads short8 (16B).
__global__ __launch_bounds__(256) void agg_csr_kernel(const ushort* __restrict__ XW,
                                                      const int2* __restrict__ csr,
                                                      const int* __restrict__ rs,
                                                      ushort* __restrict__ out) {
    int d = blockIdx.x * 4 + (threadIdx.x >> 6);
    if (d >= NN) return;
    int l = threadIdx.x & 63;
    int h = l >> 5;          // half: 0 = even edges, 1 = odd edges
    int il = l & 31;         // feature chunk: 8 bf16 at il*8
    int beg = rs[d], end = rs[d + 1];
    float a0 = 0.f, a1 = 0.f, a2 = 0.f, a3 = 0.f;
    float a4 = 0.f, a5 = 0.f, a6 = 0.f, a7 = 0.f;
    int i = beg + h;
    for (; i + 6 < end; i += 8) {
        int2 e0 = csr[i],     e1 = csr[i + 2];
        int2 e2 = csr[i + 4], e3 = csr[i + 6];
        float v0 = __int_as_float(e0.y), v1 = __int_as_float(e1.y);
        float v2 = __int_as_float(e2.y), v3 = __int_as_float(e3.y);
        short8 x0 = *(const short8*)&XW[(size_t)e0.x * D + il * 8];
        short8 x1 = *(const short8*)&XW[(size_t)e1.x * D + il * 8];
        short8 x2 = *(const short8*)&XW[(size_t)e2.x * D + il * 8];
        short8 x3 = *(const short8*)&XW[(size_t)e3.x * D + il * 8];
        a0 += v0 * bf2f((ushort)x0[0]) + v1 * bf2f((ushort)x1[0]) + v2 * bf2f((ushort)x2[0]) + v3 * bf2f((ushort)x3[0]);
        a1 += v0 * bf2f((ushort)x0[1]) + v1 * bf2f((ushort)x1[1]) + v2 * bf2f((ushort)x2[1]) + v3 * bf2f((ushort)x3[1]);
        a2 += v0 * bf2f((ushort)x0[2]) + v1 * bf2f((ushort)x1[2]) + v2 * bf2f((ushort)x2[2]) + v3 * bf2f((ushort)x3[2]);
        a3 += v0 * bf2f((ushort)x0[3]) + v1 * bf2f((ushort)x1[3]) + v2 * bf2f((ushort)x2[3]) + v3 * bf2f((ushort)x3[3]);
        a4 += v0 * bf2f((ushort)x0[4]) + v1 * bf2f((ushort)x1[4]) + v2 * bf2f((ushort)x2[4]) + v3 * bf2f((ushort)x3[4]);
        a5 += v0 * bf2f((ushort)x0[5]) + v1 * bf2f((ushort)x1[5]) + v2 * bf2f((ushort)x2[5]) + v3 * bf2f((ushort)x3[5]);
        a6 += v0 * bf2f((ushort)x0[6]) + v1 * bf2f((ushort)x1[6]) + v2 * bf2f((ushort)x2[6]) + v3 * bf2f((ushort)x3[6]);
        a7 += v0 * bf2f((ushort)x0[7]) + v1 * bf2f((ushort)x1[7]) + v2 * bf2f((ushort)x2[7]) + v3 * bf2f((ushort)x3[7]);
    }
    for (; i < end; i += 2) {
        int2 e0 = csr[i];
        float v0 = __int_as_float(e0.y);
        short8 x0 = *(const short8*)&XW[(size_t)e0.x * D + il * 8];
        a0 += v0 * bf2f((ushort)x0[0]); a1 += v0 * bf2f((ushort)x0[1]);
        a2 += v0 * bf2f((ushort)x0[2]); a3 += v0 * bf2f((ushort)x0[3]);
        a4 += v0 * bf2f((ushort)x0[4]); a5 += v0 * bf2f((ushort)x0[5]);
        a6 += v0 * bf2f((ushort)x0[6]); a7 += v0 * bf2f((ushort)x0[7]);
    }
    // combine even/odd halves (lane l <-> l^32)
    a0 += __shfl_xor(a0, 32); a1 += __shfl_xor(a1, 32);
    a2 += __shfl_xor(a2, 32); a3 += __shfl_xor(a3, 32);
    a4 += __shfl_xor(a4, 32); a5 += __shfl_xor(a5, 32);
    a6 += __shfl_xor(a6, 32); a7 += __shfl_xor(a7, 32);
    if (h == 0) {
        float r[8] = {a0, a1, a2, a3, a4, a5, a6, a7};
        short8 o;
#pragma unroll
        for (int c = 0; c < 8; ++c) {
            float v = r[c];
            v = (v >= 0.f) ? v : SLOPE_F * v;
            o[c] = (short)f2bf(v);
        }
        *(short8*)&out[(size_t)d * D + il * 8] = o;
    }
}

// ---------------- final: logits = hid@W2 + b2 ; log_softmax over 16 classes ----------------
__global__ void mlp2_kernel(const ushort* __restrict__ hid, const float* __restrict__ W2,
                            const float* __restrict__ b2, float* __restrict__ out, int M) {
    int tid = threadIdx.x;
    int n = blockIdx.x * 16 + (tid >> 4);
    int c = tid & 15;
    if (n >= M) return;
    float acc = b2[c];
    const ushort* hp = hid + (size_t)n * D;
    for (int k = 0; k < D; k += 8) {
        short8 h8 = *(const short8*)(hp + k);
#pragma unroll
        for (int u = 0; u < 8; ++u)
            acc += bf2f((ushort)h8[u]) * W2[(k + u) * 16 + c];
    }
    float m = acc;
#pragma unroll
    for (int off = 1; off < 16; off <<= 1)
        m = fmaxf(m, __shfl_xor(m, off, 16));
    float ex = expf(acc - m);
    float s = ex;
#pragma unroll
    for (int off = 1; off < 16; off <<= 1)
        s += __shfl_xor(s, off, 16);
    out[(size_t)n * 16 + c] = acc - m - logf(s);
}

extern "C" void kernel_launch(void* const* d_in, const int* in_sizes, int n_in,
                              void* d_out, int out_size, void* d_ws, size_t ws_size,
                              hipStream_t stream) {
    const float* node_feats = (const float*)d_in[0];
    const float* edge_val   = (const float*)d_in[1];
    const float* l0_Wz = (const float*)d_in[2];
    const float* l0_Uz = (const float*)d_in[3];
    const float* l0_bz = (const float*)d_in[4];
    const float* l0_Wr = (const float*)d_in[5];
    const float* l0_Ur = (const float*)d_in[6];
    const float* l0_br = (const float*)d_in[7];
    const float* l0_Wh = (const float*)d_in[8];
    const float* l0_Uh = (const float*)d_in[9];
    const float* l0_bh = (const float*)d_in[10];
    const float* l0_Q0 = (const float*)d_in[11];
    const float* l1_Wz = (const float*)d_in[12];
    const float* l1_Uz = (const float*)d_in[13];
    const float* l1_bz = (const float*)d_in[14];
    const float* l1_Wr = (const float*)d_in[15];
    const float* l1_Ur = (const float*)d_in[16];
    const float* l1_br = (const float*)d_in[17];
    const float* l1_Wh = (const float*)d_in[18];
    const float* l1_Uh = (const float*)d_in[19];
    const float* l1_bh = (const float*)d_in[20];
    const float* l1_Q0 = (const float*)d_in[21];
    const float* W1 = (const float*)d_in[22];
    const float* b1 = (const float*)d_in[23];
    const float* W2 = (const float*)d_in[24];
    const float* b2 = (const float*)d_in[25];
    const int* e_src = (const int*)d_in[26];
    const int* e_dst = (const int*)d_in[27];
    float* out = (float*)d_out;

    // workspace layout
    const size_t BIG = (size_t)NN * D;   // 12.8M elements
    ushort* XWb = (ushort*)d_ws;                 // bf16 GEMM out
    ushort* H   = XWb + BIG;                     // bf16 activations (h1/h2)
    ushort* Bt  = H + BIG;                       // 3 x 65536 bf16 (q0T, q1T, W1T)
    float*  TW  = (float*)(Bt + 3 * 65536);      // 8 x 65536 fp32 transposed GRU weights
    int2*   csr = (int2*)(TW + 8 * 65536);       // EE
    int*    deg = (int*)(csr + EE);              // NN
    int*    rs  = deg + NN;                      // NN+1
    int*    cur = rs + NN + 1;                   // NN
    int*    bsum = cur + NN;                     // 200
    int*    boff = bsum + 200;                   // 200

    // --- only timestep 5 contributes to the output ---
    const float* feats5 = node_feats + (size_t)5 * BIG;
    const int*   src5   = e_src + (size_t)5 * EE;
    const int*   dst5   = e_dst + (size_t)5 * EE;
    const float* val5   = edge_val + (size_t)5 * EE;

    // --- prep: weight transpose/merge + W1 conversion + deg zero ---
    prep_kernel<<<2500, 256, 0, stream>>>(l0_Wz, l0_Uz, l0_Wr, l0_Ur, l0_Wh, l0_Uh,
                                          l1_Wz, l1_Uz, l1_Wr, l1_Ur, l1_Wh, l1_Uh,
                                          W1, TW, Bt + 2 * 65536, deg);

    // --- full 6-step GRU for both layers, one launch ---
    gru_kernel<<<256, 256, 0, stream>>>(TW, l0_bz, l0_br, l0_bh, l0_Q0,
                                        l1_bz, l1_br, l1_bh, l1_Q0, Bt);

    // --- CSR build (reused for both layers) ---
    const int nchunks = (NN + 255) / 256;   // 196
    hist_kernel<<<(EE + 255) / 256, 256, 0, stream>>>(dst5, deg, EE);
    scanA_kernel<<<nchunks, 256, 0, stream>>>(deg, rs, bsum, NN);
    scanB_kernel<<<1, 256, 0, stream>>>(bsum, boff, rs, nchunks);
    scanC_kernel<<<nchunks, 256, 0, stream>>>(rs, cur, boff, NN);
    scatter_kernel<<<(EE + 255) / 256, 256, 0, stream>>>(src5, dst5, val5, cur, csr, EE);

    const int gemm_blocks = (NN + 63) / 64;     // 782
    const int ablocks = (NN + 3) / 4;           // 12500

    // layer 0 @ t=5 (A = fp32 feats, inline convert)
    gemm_mfma<1, 0><<<gemm_blocks, 256, 0, stream>>>(nullptr, feats5, Bt + 0 * 65536,
                                                     nullptr, XWb, NN);
    agg_csr_kernel<<<ablocks, 256, 0, stream>>>(XWb, csr, rs, H);

    // layer 1 @ t=5
    gemm_mfma<0, 0><<<gemm_blocks, 256, 0, stream>>>(H, nullptr, Bt + 1 * 65536,
                                                     nullptr, XWb, NN);
    agg_csr_kernel<<<ablocks, 256, 0, stream>>>(XWb, csr, rs, H);

    // MLP head
    gemm_mfma<0, 1><<<gemm_blocks, 256, 0, stream>>>(H, nullptr, Bt + 2 * 65536,
                                                     b1, XWb, NN);
    mlp2_kernel<<<(NN + 15) / 16, 256, 0, stream>>>(XWb, W2, b2, out, NN);
}

// Round 8
// 685.879 us; speedup vs baseline: 1.3585x; 1.1446x over previous
//
#include <hip/hip_runtime.h>
#include <cstddef>

#define SLOPE_F (11.0f / 48.0f)

static const int NN = 50000;     // nodes
static const int EE = 1600000;   // edges per timestep
static const int D  = 256;

typedef __attribute__((ext_vector_type(8))) short short8;
typedef __attribute__((ext_vector_type(4))) float f32x4;

__device__ __forceinline__ ushort f2bf(float f) {
    unsigned u = __float_as_uint(f);
    unsigned r = (u + 0x7fffu + ((u >> 16) & 1u)) >> 16;
    return (ushort)r;
}
__device__ __forceinline__ float bf2f(ushort u) {
    return __uint_as_float(((unsigned)u) << 16);
}

// ---------------- prep mega-kernel ----------------
// blocks [0,2048): transpose-merge GRU weights -> TW[mat][k][i]
// blocks [2048,2304): BtW1[n][k] = bf16(W1[k][n])
// blocks [2304,2500): zero deg
__global__ __launch_bounds__(256) void prep_kernel(
        const float* __restrict__ Wz0, const float* __restrict__ Uz0,
        const float* __restrict__ Wr0, const float* __restrict__ Ur0,
        const float* __restrict__ Wh0, const float* __restrict__ Uh0,
        const float* __restrict__ Wz1, const float* __restrict__ Uz1,
        const float* __restrict__ Wr1, const float* __restrict__ Ur1,
        const float* __restrict__ Wh1, const float* __restrict__ Uh1,
        const float* __restrict__ W1,
        float* __restrict__ TW, ushort* __restrict__ BtW1, int* __restrict__ deg) {
    int b = blockIdx.x;
    int t = threadIdx.x;
    if (b < 2048) {
        int mat = b >> 8;
        int k = b & 255;
        const float* P = nullptr; const float* S = nullptr;
        switch (mat) {
            case 0: P = Wz0; S = Uz0; break;
            case 1: P = Wr0; S = Ur0; break;
            case 2: P = Wh0; break;
            case 3: P = Uh0; break;
            case 4: P = Wz1; S = Uz1; break;
            case 5: P = Wr1; S = Ur1; break;
            case 6: P = Wh1; break;
            default: P = Uh1; break;
        }
        float v = P[t * 256 + k];
        if (S) v += S[t * 256 + k];
        TW[((size_t)mat * 256 + k) * 256 + t] = v;
    } else if (b < 2304) {
        int n = b - 2048;
        BtW1[(size_t)n * 256 + t] = f2bf(W1[t * 256 + n]);
    } else {
        int i = (b - 2304) * 256 + t;
        if (i < NN) deg[i] = 0;
    }
}

// ---------------- merged: GRU (blocks 0-255) + dst histogram (blocks 256+) ----------------
__global__ __launch_bounds__(256) void gruhist_kernel(
        const float* __restrict__ TW,
        const float* __restrict__ bz0, const float* __restrict__ br0,
        const float* __restrict__ bh0, const float* __restrict__ Q00,
        const float* __restrict__ bz1, const float* __restrict__ br1,
        const float* __restrict__ bh1, const float* __restrict__ Q01,
        ushort* __restrict__ Bt,
        const int* __restrict__ dst, int* __restrict__ deg) {
    if (blockIdx.x >= 256) {
        int e = (blockIdx.x - 256) * 256 + threadIdx.x;
        if (e < EE) atomicAdd(&deg[dst[e]], 1);
        return;
    }
    __shared__ float qs[256][2];
    __shared__ float rqs[256][2];
    int layer = blockIdx.x >> 7;
    int j0 = (blockIdx.x & 127) * 2;
    int i = threadIdx.x;
    const float* MzT = TW + (size_t)layer * 4 * 65536;
    const float* MrT = MzT + 65536;
    const float* WhT = MzT + 2 * 65536;
    const float* UhT = MzT + 3 * 65536;
    const float* bz = layer ? bz1 : bz0;
    const float* br = layer ? br1 : br0;
    const float* bh = layer ? bh1 : bh0;
    const float* Q0 = layer ? Q01 : Q00;

    float2 bzv = *(const float2*)&bz[i * 256 + j0];
    float2 brv = *(const float2*)&br[i * 256 + j0];
    float2 bhv = *(const float2*)&bh[i * 256 + j0];
    float bza[2] = {bzv.x, bzv.y};
    float bra[2] = {brv.x, brv.y};
    float bha[2] = {bhv.x, bhv.y};

    float2 qv = *(const float2*)&Q0[i * 256 + j0];
    *(float2*)&qs[i][0] = qv;
    __syncthreads();

    float qn[2] = {qv.x, qv.y};
    for (int step = 0; step < 6; ++step) {
        float az[2] = {}, ar[2] = {}, ah[2] = {};
#pragma unroll 8
        for (int k = 0; k < 256; ++k) {
            float mz = MzT[k * 256 + i];
            float mr = MrT[k * 256 + i];
            float wh = WhT[k * 256 + i];
            float2 qk = *(const float2*)&qs[k][0];
            float qa[2] = {qk.x, qk.y};
#pragma unroll
            for (int c = 0; c < 2; ++c) {
                az[c] += mz * qa[c];
                ar[c] += mr * qa[c];
                ah[c] += wh * qa[c];
            }
        }
        float z[2], qo[2];
        float2 qown = *(const float2*)&qs[i][0];
        qo[0] = qown.x; qo[1] = qown.y;
        float rq[2];
#pragma unroll
        for (int c = 0; c < 2; ++c) {
            z[c] = 1.f / (1.f + expf(-(az[c] + bza[c])));
            float r = 1.f / (1.f + expf(-(ar[c] + bra[c])));
            rq[c] = r * qo[c];
        }
        float2 rqv; rqv.x = rq[0]; rqv.y = rq[1];
        *(float2*)&rqs[i][0] = rqv;
        __syncthreads();
        float bu[2] = {};
#pragma unroll 8
        for (int k = 0; k < 256; ++k) {
            float uh = UhT[k * 256 + i];
            float2 rk = *(const float2*)&rqs[k][0];
#pragma unroll
            for (int c = 0; c < 2; ++c) bu[c] += uh * ((c == 0) ? rk.x : rk.y);
        }
        float2 qnv;
#pragma unroll
        for (int c = 0; c < 2; ++c) {
            float h = tanhf(ah[c] + bu[c] + bha[c]);
            qn[c] = (1.f - z[c]) * qo[c] + z[c] * h;
        }
        qnv.x = qn[0]; qnv.y = qn[1];
        *(float2*)&qs[i][0] = qnv;
        __syncthreads();
    }
#pragma unroll
    for (int c = 0; c < 2; ++c)
        Bt[(size_t)layer * 65536 + (size_t)(j0 + c) * 256 + i] = f2bf(qn[c]);
}

// ---------------- MFMA GEMM (no LDS; B is L1/L2-resident) ----------------
// C(bf16)[M,256] = A[M,256] @ B[256,256]; Bt: [n][k] bf16.
// 256 thr = 4 waves; wave covers 32 rows (2 A-frags share each B-frag); block = 128 rows.
template <int ASRC, int EPI>
__global__ __launch_bounds__(256) void gemm_mfma(const ushort* __restrict__ A,
                                                 const float* __restrict__ Af,
                                                 const ushort* __restrict__ Bt,
                                                 const float* __restrict__ bias,
                                                 ushort* __restrict__ C, int M) {
    int tid = threadIdx.x;
    int w = tid >> 6, l = tid & 63;
    int lr = l & 15;
    int lk = l >> 4;
    int row0 = blockIdx.x * 128 + w * 32;
    int ra = row0 + lr;      if (ra > M - 1) ra = M - 1;
    int rb = row0 + 16 + lr; if (rb > M - 1) rb = M - 1;
    const ushort* Ap0  = A  + (size_t)ra * 256 + lk * 8;
    const ushort* Ap1  = A  + (size_t)rb * 256 + lk * 8;
    const float*  Apf0 = Af + (size_t)ra * 256 + lk * 8;
    const float*  Apf1 = Af + (size_t)rb * 256 + lk * 8;
    const ushort* Bp   = Bt + (size_t)lr * 256 + lk * 8;

    f32x4 acc0[16] = {};
    f32x4 acc1[16] = {};
#pragma unroll
    for (int kc = 0; kc < 8; ++kc) {
        short8 a0, a1;
        if (ASRC == 0) {
            a0 = *(const short8*)(Ap0 + kc * 32);
            a1 = *(const short8*)(Ap1 + kc * 32);
        } else {
            float4 f0 = *(const float4*)(Apf0 + kc * 32);
            float4 f1 = *(const float4*)(Apf0 + kc * 32 + 4);
            float4 g0 = *(const float4*)(Apf1 + kc * 32);
            float4 g1 = *(const float4*)(Apf1 + kc * 32 + 4);
            a0[0] = (short)f2bf(f0.x); a0[1] = (short)f2bf(f0.y);
            a0[2] = (short)f2bf(f0.z); a0[3] = (short)f2bf(f0.w);
            a0[4] = (short)f2bf(f1.x); a0[5] = (short)f2bf(f1.y);
            a0[6] = (short)f2bf(f1.z); a0[7] = (short)f2bf(f1.w);
            a1[0] = (short)f2bf(g0.x); a1[1] = (short)f2bf(g0.y);
            a1[2] = (short)f2bf(g0.z); a1[3] = (short)f2bf(g0.w);
            a1[4] = (short)f2bf(g1.x); a1[5] = (short)f2bf(g1.y);
            a1[6] = (short)f2bf(g1.z); a1[7] = (short)f2bf(g1.w);
        }
#pragma unroll
        for (int nb = 0; nb < 16; ++nb) {
            short8 bf = *(const short8*)(Bp + (size_t)nb * 4096 + kc * 32);
            acc0[nb] = __builtin_amdgcn_mfma_f32_16x16x32_bf16(a0, bf, acc0[nb], 0, 0, 0);
            acc1[nb] = __builtin_amdgcn_mfma_f32_16x16x32_bf16(a1, bf, acc1[nb], 0, 0, 0);
        }
    }

    int ro = lk * 4;
#pragma unroll
    for (int nb = 0; nb < 16; ++nb) {
        int gc = nb * 16 + lr;
        float bb = (EPI == 1) ? bias[gc] : 0.f;
#pragma unroll
        for (int q = 0; q < 4; ++q) {
            int g0 = row0 + ro + q;
            if (g0 < M) {
                float v = acc0[nb][q];
                if (EPI == 1) v = fmaxf(v + bb, 0.f);
                C[(size_t)g0 * 256 + gc] = f2bf(v);
            }
            int g1 = row0 + 16 + ro + q;
            if (g1 < M) {
                float v = acc1[nb][q];
                if (EPI == 1) v = fmaxf(v + bb, 0.f);
                C[(size_t)g1 * 256 + gc] = f2bf(v);
            }
        }
    }
}

// ---------------- CSR build ----------------
__global__ __launch_bounds__(256) void scanA_kernel(const int* __restrict__ deg,
                                                    int* __restrict__ rs,
                                                    int* __restrict__ bsum, int n) {
    __shared__ int wsum[4];
    int tid = threadIdx.x;
    int i = blockIdx.x * 256 + tid;
    int lane = tid & 63, wv = tid >> 6;
    int v = (i < n) ? deg[i] : 0;
    int x = v;
#pragma unroll
    for (int off = 1; off < 64; off <<= 1) {
        int t = __shfl_up(x, off, 64);
        if (lane >= off) x += t;
    }
    if (lane == 63) wsum[wv] = x;
    __syncthreads();
    if (tid == 0) {
        int s = 0;
#pragma unroll
        for (int q = 0; q < 4; ++q) { int t = wsum[q]; wsum[q] = s; s += t; }
        bsum[blockIdx.x] = s;
    }
    __syncthreads();
    if (i < n) rs[i] = wsum[wv] + x - v;
}

__global__ __launch_bounds__(256) void scanB_kernel(const int* __restrict__ bsum,
                                                    int* __restrict__ boff,
                                                    int* __restrict__ rs, int nb) {
    __shared__ int wsum[4];
    int tid = threadIdx.x;
    int lane = tid & 63, wv = tid >> 6;
    int v = (tid < nb) ? bsum[tid] : 0;
    int x = v;
#pragma unroll
    for (int off = 1; off < 64; off <<= 1) {
        int t = __shfl_up(x, off, 64);
        if (lane >= off) x += t;
    }
    if (lane == 63) wsum[wv] = x;
    __syncthreads();
    if (tid == 0) {
        int s = 0;
#pragma unroll
        for (int q = 0; q < 4; ++q) { int t = wsum[q]; wsum[q] = s; s += t; }
        rs[NN] = EE;
    }
    __syncthreads();
    if (tid < nb) boff[tid] = wsum[wv] + x - v;
}

__global__ __launch_bounds__(256) void scanC_kernel(int* __restrict__ rs,
                                                    int* __restrict__ cur,
                                                    const int* __restrict__ boff, int n) {
    int i = blockIdx.x * 256 + threadIdx.x;
    if (i < n) {
        int v = rs[i] + boff[blockIdx.x];
        rs[i] = v;
        cur[i] = v;
    }
}

__global__ void scatter_kernel(const int* __restrict__ src, const int* __restrict__ dst,
                               const float* __restrict__ val, int* __restrict__ cur,
                               unsigned long long* __restrict__ csr, int nE) {
    int e = blockIdx.x * blockDim.x + threadIdx.x;
    if (e < nE) {
        int p = atomicAdd(&cur[dst[e]], 1);
        unsigned long long pk = (unsigned long long)(unsigned)src[e]
                              | ((unsigned long long)(unsigned)__float_as_uint(val[e]) << 32);
        __builtin_nontemporal_store(pk, &csr[p]);
    }
}

// ---------------- pull aggregation + fused RReLU -> bf16 out ----------------
// one wave per dst; lanes 0-31 even edges, 32-63 odd edges; 8 edges in flight per lane.
__global__ __launch_bounds__(256) void agg_csr_kernel(const ushort* __restrict__ XW,
                                                      const int2* __restrict__ csr,
                                                      const int* __restrict__ rs,
                                                      ushort* __restrict__ out) {
    int d = blockIdx.x * 4 + (threadIdx.x >> 6);
    if (d >= NN) return;
    int l = threadIdx.x & 63;
    int h = l >> 5;          // half: 0 = even edges, 1 = odd edges
    int il = l & 31;         // feature chunk: 8 bf16 at il*8
    int beg = rs[d], end = rs[d + 1];
    float a0 = 0.f, a1 = 0.f, a2 = 0.f, a3 = 0.f;
    float a4 = 0.f, a5 = 0.f, a6 = 0.f, a7 = 0.f;
    int i = beg + h;
    for (; i + 14 < end; i += 16) {
        int2 e[8];
        short8 x[8];
#pragma unroll
        for (int u = 0; u < 8; ++u) e[u] = csr[i + 2 * u];
#pragma unroll
        for (int u = 0; u < 8; ++u)
            x[u] = *(const short8*)&XW[(size_t)e[u].x * D + il * 8];
#pragma unroll
        for (int u = 0; u < 8; ++u) {
            float v = __int_as_float(e[u].y);
            a0 += v * bf2f((ushort)x[u][0]);
            a1 += v * bf2f((ushort)x[u][1]);
            a2 += v * bf2f((ushort)x[u][2]);
            a3 += v * bf2f((ushort)x[u][3]);
            a4 += v * bf2f((ushort)x[u][4]);
            a5 += v * bf2f((ushort)x[u][5]);
            a6 += v * bf2f((ushort)x[u][6]);
            a7 += v * bf2f((ushort)x[u][7]);
        }
    }
    for (; i + 6 < end; i += 8) {
        int2 e[4];
        short8 x[4];
#pragma unroll
        for (int u = 0; u < 4; ++u) e[u] = csr[i + 2 * u];
#pragma unroll
        for (int u = 0; u < 4; ++u)
            x[u] = *(const short8*)&XW[(size_t)e[u].x * D + il * 8];
#pragma unroll
        for (int u = 0; u < 4; ++u) {
            float v = __int_as_float(e[u].y);
            a0 += v * bf2f((ushort)x[u][0]);
            a1 += v * bf2f((ushort)x[u][1]);
            a2 += v * bf2f((ushort)x[u][2]);
            a3 += v * bf2f((ushort)x[u][3]);
            a4 += v * bf2f((ushort)x[u][4]);
            a5 += v * bf2f((ushort)x[u][5]);
            a6 += v * bf2f((ushort)x[u][6]);
            a7 += v * bf2f((ushort)x[u][7]);
        }
    }
    for (; i < end; i += 2) {
        int2 e0 = csr[i];
        float v0 = __int_as_float(e0.y);
        short8 x0 = *(const short8*)&XW[(size_t)e0.x * D + il * 8];
        a0 += v0 * bf2f((ushort)x0[0]); a1 += v0 * bf2f((ushort)x0[1]);
        a2 += v0 * bf2f((ushort)x0[2]); a3 += v0 * bf2f((ushort)x0[3]);
        a4 += v0 * bf2f((ushort)x0[4]); a5 += v0 * bf2f((ushort)x0[5]);
        a6 += v0 * bf2f((ushort)x0[6]); a7 += v0 * bf2f((ushort)x0[7]);
    }
    a0 += __shfl_xor(a0, 32); a1 += __shfl_xor(a1, 32);
    a2 += __shfl_xor(a2, 32); a3 += __shfl_xor(a3, 32);
    a4 += __shfl_xor(a4, 32); a5 += __shfl_xor(a5, 32);
    a6 += __shfl_xor(a6, 32); a7 += __shfl_xor(a7, 32);
    if (h == 0) {
        float r[8] = {a0, a1, a2, a3, a4, a5, a6, a7};
        short8 o;
#pragma unroll
        for (int c = 0; c < 8; ++c) {
            float v = r[c];
            v = (v >= 0.f) ? v : SLOPE_F * v;
            o[c] = (short)f2bf(v);
        }
        *(short8*)&out[(size_t)d * D + il * 8] = o;
    }
}

// ---------------- final: logits = hid@W2 + b2 ; log_softmax over 16 classes ----------------
__global__ void mlp2_kernel(const ushort* __restrict__ hid, const float* __restrict__ W2,
                            const float* __restrict__ b2, float* __restrict__ out, int M) {
    int tid = threadIdx.x;
    int n = blockIdx.x * 16 + (tid >> 4);
    int c = tid & 15;
    if (n >= M) return;
    float acc = b2[c];
    const ushort* hp = hid + (size_t)n * D;
    for (int k = 0; k < D; k += 8) {
        short8 h8 = *(const short8*)(hp + k);
#pragma unroll
        for (int u = 0; u < 8; ++u)
            acc += bf2f((ushort)h8[u]) * W2[(k + u) * 16 + c];
    }
    float m = acc;
#pragma unroll
    for (int off = 1; off < 16; off <<= 1)
        m = fmaxf(m, __shfl_xor(m, off, 16));
    float ex = expf(acc - m);
    float s = ex;
#pragma unroll
    for (int off = 1; off < 16; off <<= 1)
        s += __shfl_xor(s, off, 16);
    out[(size_t)n * 16 + c] = acc - m - logf(s);
}

extern "C" void kernel_launch(void* const* d_in, const int* in_sizes, int n_in,
                              void* d_out, int out_size, void* d_ws, size_t ws_size,
                              hipStream_t stream) {
    const float* node_feats = (const float*)d_in[0];
    const float* edge_val   = (const float*)d_in[1];
    const float* l0_Wz = (const float*)d_in[2];
    const float* l0_Uz = (const float*)d_in[3];
    const float* l0_bz = (const float*)d_in[4];
    const float* l0_Wr = (const float*)d_in[5];
    const float* l0_Ur = (const float*)d_in[6];
    const float* l0_br = (const float*)d_in[7];
    const float* l0_Wh = (const float*)d_in[8];
    const float* l0_Uh = (const float*)d_in[9];
    const float* l0_bh = (const float*)d_in[10];
    const float* l0_Q0 = (const float*)d_in[11];
    const float* l1_Wz = (const float*)d_in[12];
    const float* l1_Uz = (const float*)d_in[13];
    const float* l1_bz = (const float*)d_in[14];
    const float* l1_Wr = (const float*)d_in[15];
    const float* l1_Ur = (const float*)d_in[16];
    const float* l1_br = (const float*)d_in[17];
    const float* l1_Wh = (const float*)d_in[18];
    const float* l1_Uh = (const float*)d_in[19];
    const float* l1_bh = (const float*)d_in[20];
    const float* l1_Q0 = (const float*)d_in[21];
    const float* W1 = (const float*)d_in[22];
    const float* b1 = (const float*)d_in[23];
    const float* W2 = (const float*)d_in[24];
    const float* b2 = (const float*)d_in[25];
    const int* e_src = (const int*)d_in[26];
    const int* e_dst = (const int*)d_in[27];
    float* out = (float*)d_out;

    // workspace layout
    const size_t BIG = (size_t)NN * D;   // 12.8M elements
    ushort* XWb = (ushort*)d_ws;                 // bf16 GEMM out
    ushort* H   = XWb + BIG;                     // bf16 activations (h1/h2)
    ushort* Bt  = H + BIG;                       // 3 x 65536 bf16 (q0T, q1T, W1T)
    float*  TW  = (float*)(Bt + 3 * 65536);      // 8 x 65536 fp32 transposed GRU weights
    int2*   csr = (int2*)(TW + 8 * 65536);       // EE
    int*    deg = (int*)(csr + EE);              // NN
    int*    rs  = deg + NN;                      // NN+1
    int*    cur = rs + NN + 1;                   // NN
    int*    bsum = cur + NN;                     // 200
    int*    boff = bsum + 200;                   // 200

    // --- only timestep 5 contributes to the output ---
    const float* feats5 = node_feats + (size_t)5 * BIG;
    const int*   src5   = e_src + (size_t)5 * EE;
    const int*   dst5   = e_dst + (size_t)5 * EE;
    const float* val5   = edge_val + (size_t)5 * EE;

    // --- prep: weight transpose/merge + W1 conversion + deg zero ---
    prep_kernel<<<2500, 256, 0, stream>>>(l0_Wz, l0_Uz, l0_Wr, l0_Ur, l0_Wh, l0_Uh,
                                          l1_Wz, l1_Uz, l1_Wr, l1_Ur, l1_Wh, l1_Uh,
                                          W1, TW, Bt + 2 * 65536, deg);

    // --- GRU (256 blocks) + dst histogram (6250 blocks) in one launch ---
    const int histblocks = (EE + 255) / 256;
    gruhist_kernel<<<256 + histblocks, 256, 0, stream>>>(TW, l0_bz, l0_br, l0_bh, l0_Q0,
                                                         l1_bz, l1_br, l1_bh, l1_Q0, Bt,
                                                         dst5, deg);

    // --- CSR scan + scatter ---
    const int nchunks = (NN + 255) / 256;   // 196
    scanA_kernel<<<nchunks, 256, 0, stream>>>(deg, rs, bsum, NN);
    scanB_kernel<<<1, 256, 0, stream>>>(bsum, boff, rs, nchunks);
    scanC_kernel<<<nchunks, 256, 0, stream>>>(rs, cur, boff, NN);
    scatter_kernel<<<(EE + 255) / 256, 256, 0, stream>>>(src5, dst5, val5, cur,
                                                         (unsigned long long*)csr, EE);

    const int gemm_blocks = (NN + 127) / 128;   // 391
    const int ablocks = (NN + 3) / 4;           // 12500

    // layer 0 @ t=5 (A = fp32 feats, inline convert)
    gemm_mfma<1, 0><<<gemm_blocks, 256, 0, stream>>>(nullptr, feats5, Bt + 0 * 65536,
                                                     nullptr, XWb, NN);
    agg_csr_kernel<<<ablocks, 256, 0, stream>>>(XWb, csr, rs, H);

    // layer 1 @ t=5
    gemm_mfma<0, 0><<<gemm_blocks, 256, 0, stream>>>(H, nullptr, Bt + 1 * 65536,
                                                     nullptr, XWb, NN);
    agg_csr_kernel<<<ablocks, 256, 0, stream>>>(XWb, csr, rs, H);

    // MLP head
    gemm_mfma<0, 1><<<gemm_blocks, 256, 0, stream>>>(H, nullptr, Bt + 2 * 65536,
                                                     b1, XWb, NN);
    mlp2_kernel<<<(NN + 15) / 16, 256, 0, stream>>>(XWb, W2, b2, out, NN);
}